// Round 2
// baseline (1210.832 us; speedup 1.0000x reference)
//
#include <hip/hip_runtime.h>
#include <hip/hip_bf16.h>

// B=512, I=1152, K=8, L=16, O=7; IK=9216, LO=112. All fp32.
// Restructured routing (u_hat [B,I,l,O] never materialized):
//   wc[ik,lo]  = c[i,l] * w[ik,lo]            (w native layout is [ik][l*7+o])
//   s[b,lo]    = sum_ik x[b,ik] * wc[ik,lo]
//   v[b,o*16+l]= squash(s)[b,l,o] transposed  (also the final output layout)
//   G[ik,o*16+l]= sum_b x[b,ik] * v[b,o*16+l]
//   b[i,l]    += (1/512) sum_{k,o} w[ik,l*7+o] * G[ik,o*16+l]
// Iter 3's b-update is dead code -> skipped.

#define NB 512
#define NI 1152
#define NK 8
#define NL 16
#define NO 7
#define NLO 112
#define NIK 9216

// ---- c[i,l] = softmax over i of b[i,l] ----
__global__ void softmax_col(const float* __restrict__ b, float* __restrict__ c) {
    int l = blockIdx.x;          // 16 blocks
    int t = threadIdx.x;         // 256 threads
    __shared__ float red[256];
    float m = -1e30f;
    for (int i = t; i < NI; i += 256) m = fmaxf(m, b[i * NL + l]);
    red[t] = m; __syncthreads();
    for (int s = 128; s > 0; s >>= 1) {
        if (t < s) red[t] = fmaxf(red[t], red[t + s]);
        __syncthreads();
    }
    m = red[0]; __syncthreads();
    float sum = 0.f;
    for (int i = t; i < NI; i += 256) sum += expf(b[i * NL + l] - m);
    red[t] = sum; __syncthreads();
    for (int s = 128; s > 0; s >>= 1) {
        if (t < s) red[t] += red[t + s];
        __syncthreads();
    }
    float inv = 1.0f / red[0];
    for (int i = t; i < NI; i += 256) c[i * NL + l] = expf(b[i * NL + l] - m) * inv;
}

// ---- wc[ik*112 + lo] = c[i,l] * w[ik*112 + lo] ----
__global__ void wc_mul(const float* __restrict__ c, const float* __restrict__ w,
                       float* __restrict__ wc) {
    int e = blockIdx.x * 256 + threadIdx.x;   // 4032*256 == 1032192 exactly
    int ik = e / NLO;
    int lo = e - ik * NLO;
    int i = ik >> 3;
    int l = lo / NO;
    wc[e] = c[i * NL + l] * w[e];
}

// ---- s[b,lo] = sum_ik x[b,ik]*wc[ik,lo]; 4 batches per block, 128 blocks ----
__global__ __launch_bounds__(256) void s_gemm(const float* __restrict__ x,
                                              const float* __restrict__ wc,
                                              float* __restrict__ s) {
    __shared__ float xs[2304 * 4];   // [ik_local][b] transposed, 36 KB
    __shared__ float4 part[256];     // 4 KB
    int b0 = blockIdx.x * 4;
    int t = threadIdx.x;
    int lo = t % NLO;                // 0..111
    int seg = t / NLO;               // 0,1 compute; 2 idle in compute phase
    float4 acc = {0.f, 0.f, 0.f, 0.f};
    for (int ck = 0; ck < 4; ++ck) {
        __syncthreads();
        // stage x[b0..b0+3][ck*2304 .. +2304] transposed into xs[ik][b]
        for (int idx = t; idx < 2304; idx += 256) {
            int r = idx / 576;       // batch 0..3
            int c4 = idx - r * 576;  // float4 index within row chunk
            const float4 xv = *(const float4*)(x + (size_t)(b0 + r) * NIK + ck * 2304 + c4 * 4);
            int base = c4 * 4;
            xs[(base    ) * 4 + r] = xv.x;
            xs[(base + 1) * 4 + r] = xv.y;
            xs[(base + 2) * 4 + r] = xv.z;
            xs[(base + 3) * 4 + r] = xv.w;
        }
        __syncthreads();
        if (seg < 2) {
            const float* wp = wc + (size_t)(ck * 2304 + seg * 1152) * NLO + lo;
            const float4* xp = (const float4*)xs + seg * 1152;
            #pragma unroll 4
            for (int ik = 0; ik < 1152; ++ik) {
                float wv = wp[(size_t)ik * NLO];
                float4 xv = xp[ik];
                acc.x += xv.x * wv;
                acc.y += xv.y * wv;
                acc.z += xv.z * wv;
                acc.w += xv.w * wv;
            }
        }
    }
    part[t] = acc;
    __syncthreads();
    if (t < NLO) {
        float4 a = part[t], b = part[t + NLO];
        s[(size_t)(b0 + 0) * NLO + t] = a.x + b.x;
        s[(size_t)(b0 + 1) * NLO + t] = a.y + b.y;
        s[(size_t)(b0 + 2) * NLO + t] = a.z + b.z;
        s[(size_t)(b0 + 3) * NLO + t] = a.w + b.w;
    }
}

// ---- squash + transpose: v[b,o*16+l] = s[b,l*7+o]*sqrt(sq)/(1+sq) ----
__global__ void squash_k(const float* __restrict__ s, float* __restrict__ v,
                         float* __restrict__ out, int write_out) {
    int b = blockIdx.x;          // 512 blocks, 128 threads
    int t = threadIdx.x;
    __shared__ float sh[NLO];
    __shared__ float fac[NL];
    float sv = 0.f;
    if (t < NLO) { sv = s[(size_t)b * NLO + t]; sh[t] = sv; }
    __syncthreads();
    if (t < NL) {
        float sq = 0.f;
        #pragma unroll
        for (int o = 0; o < NO; ++o) { float e = sh[t * NO + o]; sq += e * e; }
        fac[t] = sqrtf(sq) / (1.0f + sq);   // == (sq/(1+sq))/norm
    }
    __syncthreads();
    if (t < NLO) {
        int l = t / NO, o = t - l * NO;
        float vv = sv * fac[l];
        v[(size_t)b * NLO + o * NL + l] = vv;
        if (write_out) out[(size_t)b * NLO + o * NL + l] = vv;
    }
}

// ---- G[ik,o*16+l] = sum_b x[b,ik]*v[b,o*16+l]; 64 rows x 112 cols per block ----
__global__ __launch_bounds__(256) void g_gemm(const float* __restrict__ x,
                                              const float* __restrict__ v,
                                              float* __restrict__ G) {
    __shared__ float vs[128 * NLO];   // 57344 B
    __shared__ float xsh[128 * 64];   // 32768 B
    int row0 = blockIdx.x * 64;       // 144 blocks cover 9216 rows
    int t = threadIdx.x;
    int rg = t >> 3;   // 0..31 -> rows rg*2 + {0,1}
    int cg = t & 7;    // 0..7  -> cols cg*14 + {0..13}
    float acc0[14] = {};
    float acc1[14] = {};
    for (int bc = 0; bc < NB; bc += 128) {
        __syncthreads();
        {
            const float4* vsrc = (const float4*)(v + (size_t)bc * NLO);
            float4* vdst = (float4*)vs;
            for (int idx = t; idx < 128 * NLO / 4; idx += 256) vdst[idx] = vsrc[idx];
        }
        {
            int bl = t >> 1, half = t & 1;   // 32 floats = 8 float4 per thread
            const float4* s4 = (const float4*)(x + (size_t)(bc + bl) * NIK + row0 + half * 32);
            float4* d4 = (float4*)(xsh + bl * 64 + half * 32);
            #pragma unroll
            for (int j = 0; j < 8; ++j) d4[j] = s4[j];
        }
        __syncthreads();
        for (int bl = 0; bl < 128; ++bl) {
            float xv0 = xsh[bl * 64 + rg * 2];
            float xv1 = xsh[bl * 64 + rg * 2 + 1];
            const float* vr = &vs[bl * NLO + cg * 14];
            #pragma unroll
            for (int c = 0; c < 14; ++c) {
                float vv = vr[c];
                acc0[c] += xv0 * vv;
                acc1[c] += xv1 * vv;
            }
        }
    }
    #pragma unroll
    for (int c = 0; c < 14; ++c) {
        G[(size_t)(row0 + rg * 2    ) * NLO + cg * 14 + c] = acc0[c];
        G[(size_t)(row0 + rg * 2 + 1) * NLO + cg * 14 + c] = acc1[c];
    }
}

// ---- b[i,l] += (1/512) * sum_{k,o} w[ik,l*7+o] * G[ik,o*16+l] ----
__global__ void uvj_k(const float* __restrict__ w, const float* __restrict__ G,
                      float* __restrict__ b) {
    int il = blockIdx.x * 256 + threadIdx.x;   // 72*256 == 18432 exactly
    int i = il >> 4, l = il & 15;
    float acc = 0.f;
    #pragma unroll
    for (int k = 0; k < NK; ++k) {
        int ik = i * NK + k;
        const float* wr = w + (size_t)ik * NLO + l * NO;
        const float* Gr = G + (size_t)ik * NLO + l;
        #pragma unroll
        for (int o = 0; o < NO; ++o)
            acc += wr[o] * Gr[o * NL];
    }
    b[il] += acc * (1.0f / 512.0f);
}

extern "C" void kernel_launch(void* const* d_in, const int* in_sizes, int n_in,
                              void* d_out, int out_size, void* d_ws, size_t ws_size,
                              hipStream_t stream) {
    const float* x = (const float*)d_in[0];   // [512,1152,8]
    const float* w = (const float*)d_in[1];   // [1152,8,16,7]
    float* out = (float*)d_out;               // [512,7,16]
    float* ws = (float*)d_ws;
    float* f_b  = ws;                 // 18432
    float* f_c  = f_b  + 18432;       // 18432
    float* f_wc = f_c  + 18432;       // 1032192
    float* f_s  = f_wc + 1032192;     // 57344
    float* f_v  = f_s  + 57344;       // 57344
    float* f_G  = f_v  + 57344;       // 1032192
    hipMemsetAsync(f_b, 0, 18432 * sizeof(float), stream);
    for (int it = 0; it < 3; ++it) {
        softmax_col<<<16, 256, 0, stream>>>(f_b, f_c);
        wc_mul<<<4032, 256, 0, stream>>>(f_c, w, f_wc);
        s_gemm<<<128, 256, 0, stream>>>(x, f_wc, f_s);
        squash_k<<<512, 128, 0, stream>>>(f_s, f_v, out, it == 2 ? 1 : 0);
        if (it < 2) {
            g_gemm<<<144, 256, 0, stream>>>(x, f_v, f_G);
            uvj_k<<<72, 256, 0, stream>>>(w, f_G, f_b);
        }
    }
}

// Round 3
// 622.777 us; speedup vs baseline: 1.9442x; 1.9442x over previous
//
#include <hip/hip_runtime.h>
#include <hip/hip_bf16.h>

// B=512, I=1152, K=8, L=16, O=7; IK=9216, LO=112. All fp32.
// u_hat is never materialized; wc is never materialized (c folded in-loop).
//   s[b,lo]     = sum_i c[i,l] * (sum_{k in i} x[b,ik] * w[ik,lo])
//   v[b,o16+l]  = squash(s) transposed (== output layout)
//   b[i,l]     += (1/512) sum_{k,o} w[ik,l*7+o] * (sum_b x[b,ik]*v[b,o16+l])
// Iter 3's b-update is dead code -> skipped.

#define NB 512
#define NI 1152
#define NK 8
#define NL 16
#define NO 7
#define NLO 112
#define NIK 9216

// ---- c[i,l] = softmax over i of b[i,l] ----
__global__ void softmax_col(const float* __restrict__ b, float* __restrict__ c) {
    int l = blockIdx.x;          // 16 blocks
    int t = threadIdx.x;         // 256 threads
    __shared__ float red[256];
    float m = -1e30f;
    for (int i = t; i < NI; i += 256) m = fmaxf(m, b[i * NL + l]);
    red[t] = m; __syncthreads();
    for (int s = 128; s > 0; s >>= 1) {
        if (t < s) red[t] = fmaxf(red[t], red[t + s]);
        __syncthreads();
    }
    m = red[0]; __syncthreads();
    float sum = 0.f;
    for (int i = t; i < NI; i += 256) sum += expf(b[i * NL + l] - m);
    red[t] = sum; __syncthreads();
    for (int s = 128; s > 0; s >>= 1) {
        if (t < s) red[t] += red[t + s];
        __syncthreads();
    }
    float inv = 1.0f / red[0];
    for (int i = t; i < NI; i += 256) c[i * NL + l] = expf(b[i * NL + l] - m) * inv;
}

// ---- s_gemm: grid 576 = 72 K-chunks x 8 b-groups; K-split partials via atomicAdd ----
// s[b0+4bq+j][loq*7+o] += sum over k-chunk of c[i,loq]*x[b][k]*w[k][loq*7+o]
__global__ __launch_bounds__(256) void s_gemm(const float* __restrict__ x,
                                              const float* __restrict__ w,
                                              const float* __restrict__ c,
                                              float* __restrict__ s) {
    __shared__ float xs[128 * 68];   // [k][b], pad 68 -> 16B-aligned rows, 34.8 KB
    int bg = blockIdx.x & 7;         // 8 groups of 64 batches
    int kc = blockIdx.x >> 3;        // 72 chunks of 128 k
    int b0 = bg * 64;
    int k0 = kc * 128;
    int t = threadIdx.x;
    // stage x[b0..+63][k0..+127] transposed -> xs[k][b] (scalar r/w)
    for (int idx = t; idx < 8192; idx += 256) {
        int b = idx >> 7;            // 0..63
        int k = idx & 127;           // 0..127
        xs[k * 68 + b] = x[(size_t)(b0 + b) * NIK + k0 + k];
    }
    __syncthreads();
    int bq  = t & 15;                // 4 batches each
    int loq = t >> 4;                // == l (0..15), 7 outputs each
    float acc[4][7] = {};
    for (int ig = 0; ig < 16; ++ig) {       // i-groups within chunk
        float inner[4][7] = {};
        #pragma unroll 2
        for (int kk = 0; kk < 8; ++kk) {
            int k = ig * 8 + kk;
            float4 x4 = *(const float4*)&xs[k * 68 + bq * 4];
            const float* wr = w + (size_t)(k0 + k) * NLO + loq * 7;
            #pragma unroll
            for (int o = 0; o < 7; ++o) {
                float wv = wr[o];
                inner[0][o] += x4.x * wv;
                inner[1][o] += x4.y * wv;
                inner[2][o] += x4.z * wv;
                inner[3][o] += x4.w * wv;
            }
        }
        float cv = c[(kc * 16 + ig) * NL + loq];
        #pragma unroll
        for (int j = 0; j < 4; ++j)
            #pragma unroll
            for (int o = 0; o < 7; ++o)
                acc[j][o] += cv * inner[j][o];
    }
    #pragma unroll
    for (int j = 0; j < 4; ++j)
        #pragma unroll
        for (int o = 0; o < 7; ++o)
            atomicAdd(&s[(size_t)(b0 + bq * 4 + j) * NLO + loq * 7 + o], acc[j][o]);
}

// ---- squash + transpose: v[b,o*16+l] = s[b,l*7+o]*sqrt(sq)/(1+sq) ----
__global__ void squash_k(const float* __restrict__ s, float* __restrict__ v,
                         float* __restrict__ out, int write_out) {
    int b = blockIdx.x;          // 512 blocks, 128 threads
    int t = threadIdx.x;
    __shared__ float sh[NLO];
    __shared__ float fac[NL];
    float sv = 0.f;
    if (t < NLO) { sv = s[(size_t)b * NLO + t]; sh[t] = sv; }
    __syncthreads();
    if (t < NL) {
        float sq = 0.f;
        #pragma unroll
        for (int o = 0; o < NO; ++o) { float e = sh[t * NO + o]; sq += e * e; }
        fac[t] = sqrtf(sq) / (1.0f + sq);   // == (sq/(1+sq))/norm
    }
    __syncthreads();
    if (t < NLO) {
        int l = t / NO, o = t - l * NO;
        float vv = sv * fac[l];
        v[(size_t)b * NLO + o * NL + l] = vv;
        if (write_out) out[(size_t)b * NLO + o * NL + l] = vv;
    }
}

// ---- fused G-tile + w-contraction -> b update. grid 1152 = 144 m-groups x 8 k-chunks ----
// G[ik, o*16+l] = sum_b x[b,ik]*v[b,o*16+l]; b[i,l] += (1/512)*sum_{k,o} w[ik,l*7+o]*G
__global__ __launch_bounds__(256) void g_fused(const float* __restrict__ x,
                                               const float* __restrict__ v,
                                               const float* __restrict__ w,
                                               float* __restrict__ bij) {
    __shared__ float xs2[64 * 64];    // [kb][m]  16 KB
    __shared__ float vs[64 * NLO];    // [kb][112] 28.7 KB
    __shared__ float bs[128];         // [i_local][l]
    int kg = blockIdx.x & 7;          // 8 chunks of 64 batches
    int mg = blockIdx.x >> 3;         // 144 groups of 64 ik
    int m0 = mg * 64;
    int kb0 = kg * 64;
    int t = threadIdx.x;
    if (t < 128) bs[t] = 0.f;
    // stage x[kb0..+63][m0..+63] and v[kb0..+63][0..111], both f4 straight copies
    for (int idx = t; idx < 1024; idx += 256) {
        int k = idx >> 4, mq = idx & 15;
        *(float4*)&xs2[k * 64 + mq * 4] =
            *(const float4*)(x + (size_t)(kb0 + k) * NIK + m0 + mq * 4);
    }
    for (int idx = t; idx < 64 * 28; idx += 256) {
        int k = idx / 28, cq = idx - k * 28;
        *(float4*)&vs[k * NLO + cq * 4] =
            *(const float4*)(v + (size_t)(kb0 + k) * NLO + cq * 4);
    }
    __syncthreads();
    int mq = t & 15;                  // 4 ik rows each
    int lq = t >> 4;                  // l = lq, cols o*16+lq
    float acc[4][7] = {};
    for (int k = 0; k < 64; ++k) {
        float4 x4 = *(const float4*)&xs2[k * 64 + mq * 4];
        const float* vr = &vs[k * NLO + lq];
        #pragma unroll
        for (int o = 0; o < 7; ++o) {
            float vv = vr[o * NL];
            acc[0][o] += x4.x * vv;
            acc[1][o] += x4.y * vv;
            acc[2][o] += x4.z * vv;
            acc[3][o] += x4.w * vv;
        }
    }
    // contract with w: bs[i_local][lq] += sum_{j,o} w[ik, lq*7+o]*acc[j][o]
    float wsum = 0.f;
    #pragma unroll
    for (int j = 0; j < 4; ++j) {
        int ik = m0 + mq * 4 + j;
        const float* wr = w + (size_t)ik * NLO + lq * 7;
        #pragma unroll
        for (int o = 0; o < 7; ++o) wsum += wr[o] * acc[j][o];
    }
    int i_local = mq >> 1;            // (mq*4+j)/8, same for j=0..3
    atomicAdd(&bs[i_local * NL + lq], wsum);
    __syncthreads();
    if (t < 128)
        atomicAdd(&bij[(size_t)(m0 / 8 + (t >> 4)) * NL + (t & 15)], bs[t] * (1.0f / 512.0f));
}

extern "C" void kernel_launch(void* const* d_in, const int* in_sizes, int n_in,
                              void* d_out, int out_size, void* d_ws, size_t ws_size,
                              hipStream_t stream) {
    const float* x = (const float*)d_in[0];   // [512,1152,8] = [512][9216]
    const float* w = (const float*)d_in[1];   // [1152,8,16,7] = [9216][112]
    float* out = (float*)d_out;               // [512,7,16]
    float* ws = (float*)d_ws;
    float* f_b = ws;                  // 18432
    float* f_c = f_b + 18432;         // 18432
    float* f_s = f_c + 18432;         // 57344
    float* f_v = f_s + 57344;         // 57344
    hipMemsetAsync(f_b, 0, 18432 * sizeof(float), stream);
    for (int it = 0; it < 3; ++it) {
        hipMemsetAsync(f_s, 0, 57344 * sizeof(float), stream);
        softmax_col<<<16, 256, 0, stream>>>(f_b, f_c);
        s_gemm<<<576, 256, 0, stream>>>(x, w, f_c, f_s);
        squash_k<<<512, 128, 0, stream>>>(f_s, f_v, out, it == 2 ? 1 : 0);
        if (it < 2) g_fused<<<1152, 256, 0, stream>>>(x, f_v, w, f_b);
    }
}

// Round 4
// 321.807 us; speedup vs baseline: 3.7626x; 1.9353x over previous
//
#include <hip/hip_runtime.h>
#include <hip/hip_bf16.h>

// B=512, I=1152, K=8, L=16, O=7; IK=9216, LO=112. All fp32.
// u_hat never materialized; wc never materialized (c folded per i-group).
//   s[b,lo]    = sum_i c[i,l] * (sum_{k in i} x[b,ik] * w[ik,lo])   (K-split partials)
//   v[b,o16+l] = squash(s) transposed (== output layout)            (reduce fused here)
//   b[i,l]    += (1/512) sum_{k,o} w[ik,l*7+o] * (sum_b x[b,ik]*v[b,o16+l])
// Iter 3's b-update is dead code -> skipped.

#define NB 512
#define NI 1152
#define NK 8
#define NL 16
#define NO 7
#define NLO 112
#define NIK 9216
#define KSPLIT 36            // 36 chunks of 256 k
#define SPART 57344          // 512*112

// ---- c[i,l] = softmax over i of b[i,l] ----
__global__ void softmax_col(const float* __restrict__ b, float* __restrict__ c) {
    int l = blockIdx.x;          // 16 blocks
    int t = threadIdx.x;         // 256 threads
    __shared__ float red[256];
    float m = -1e30f;
    for (int i = t; i < NI; i += 256) m = fmaxf(m, b[i * NL + l]);
    red[t] = m; __syncthreads();
    for (int s = 128; s > 0; s >>= 1) {
        if (t < s) red[t] = fmaxf(red[t], red[t + s]);
        __syncthreads();
    }
    m = red[0]; __syncthreads();
    float sum = 0.f;
    for (int i = t; i < NI; i += 256) sum += expf(b[i * NL + l] - m);
    red[t] = sum; __syncthreads();
    for (int s = 128; s > 0; s >>= 1) {
        if (t < s) red[t] += red[t + s];
        __syncthreads();
    }
    float inv = 1.0f / red[0];
    for (int i = t; i < NI; i += 256) c[i * NL + l] = expf(b[i * NL + l] - m) * inv;
}

// ---- s_gemm: grid 1152 = 36 K-chunks x 32 b-groups; all-LDS inner loop ----
// part[kc][b0+bq][loq*7+o] = sum over 256-k chunk of c[i,l]*x[b][k]*w[k][lo]
__global__ __launch_bounds__(256) void s_gemm(const float* __restrict__ x,
                                              const float* __restrict__ w,
                                              const float* __restrict__ c,
                                              float* __restrict__ part) {
    __shared__ float xs[64 * 20];     // [k][b] pad 16->20, 5 KB
    __shared__ float wsh[64 * 128];   // [k][l*8+o] pad 7->8, 32 KB
    __shared__ float cs[32 * 16];     // [i_local][l], 2 KB
    int bg = blockIdx.x & 31;         // 32 groups of 16 batches
    int kc = blockIdx.x >> 5;         // 36 chunks of 256 k
    int b0 = bg * 16;
    int k0 = kc * 256;
    int t = threadIdx.x;
    // stage c for this chunk's 32 i's (contiguous rows of c)
    for (int idx = t; idx < 512; idx += 256) cs[idx] = c[(size_t)(kc * 32) * NL + idx];
    int bq  = t & 15;                 // 1 batch each
    int loq = t >> 4;                 // == l (0..15), 7 outputs each
    float acc[7] = {};
    for (int ss = 0; ss < 4; ++ss) {
        __syncthreads();
        // stage x[b0..+15][64k] transposed -> xs[k][b]
        for (int idx = t; idx < 1024; idx += 256) {
            int b = idx >> 6, k = idx & 63;
            xs[k * 20 + b] = x[(size_t)(b0 + b) * NIK + k0 + ss * 64 + k];
        }
        // stage w[64k][112] -> wsh[k][l*8+o]
        for (int idx = t; idx < 7168; idx += 256) {
            int k = idx / NLO;
            int lo = idx - k * NLO;
            int l = lo / NO;
            wsh[k * 128 + l * 8 + (lo - l * NO)] = w[(size_t)(k0 + ss * 64 + k) * NLO + lo];
        }
        __syncthreads();
        #pragma unroll
        for (int ig = 0; ig < 8; ++ig) {
            float inner[7] = {};
            #pragma unroll
            for (int kk = 0; kk < 8; ++kk) {
                int k = ig * 8 + kk;
                float xv = xs[k * 20 + bq];
                float4 wA = *(const float4*)&wsh[k * 128 + loq * 8];
                float4 wB = *(const float4*)&wsh[k * 128 + loq * 8 + 4];
                inner[0] += xv * wA.x; inner[1] += xv * wA.y;
                inner[2] += xv * wA.z; inner[3] += xv * wA.w;
                inner[4] += xv * wB.x; inner[5] += xv * wB.y;
                inner[6] += xv * wB.z;                       // wB.w is pad, unused
            }
            float cv = cs[(ss * 8 + ig) * NL + loq];
            #pragma unroll
            for (int o = 0; o < 7; ++o) acc[o] += cv * inner[o];
        }
    }
    float* pp = part + (size_t)kc * SPART + (size_t)(b0 + bq) * NLO + loq * 7;
    #pragma unroll
    for (int o = 0; o < 7; ++o) pp[o] = acc[o];
}

// ---- fused K-split reduce + squash + transpose ----
__global__ void squash_k(const float* __restrict__ part, float* __restrict__ v,
                         float* __restrict__ out, int write_out) {
    int b = blockIdx.x;          // 512 blocks, 128 threads
    int t = threadIdx.x;
    __shared__ float sh[NLO];
    __shared__ float fac[NL];
    float sv = 0.f;
    if (t < NLO) {
        const float* p = part + (size_t)b * NLO + t;
        #pragma unroll 6
        for (int kc = 0; kc < KSPLIT; ++kc) sv += p[(size_t)kc * SPART];
        sh[t] = sv;
    }
    __syncthreads();
    if (t < NL) {
        float sq = 0.f;
        #pragma unroll
        for (int o = 0; o < NO; ++o) { float e = sh[t * NO + o]; sq += e * e; }
        fac[t] = sqrtf(sq) / (1.0f + sq);   // == (sq/(1+sq))/norm
    }
    __syncthreads();
    if (t < NLO) {
        int l = t / NO, o = t - l * NO;
        float vv = sv * fac[l];
        v[(size_t)b * NLO + o * NL + l] = vv;
        if (write_out) out[(size_t)b * NLO + o * NL + l] = vv;
    }
}

// ---- fused G-tile + w-contraction -> b update. grid 1152 = 144 m-groups x 8 k-chunks ----
__global__ __launch_bounds__(256) void g_fused(const float* __restrict__ x,
                                               const float* __restrict__ v,
                                               const float* __restrict__ w,
                                               float* __restrict__ bij) {
    __shared__ float xs2[64 * 64];    // [kb][m]  16 KB
    __shared__ float vs[64 * NLO];    // [kb][112] 28.7 KB
    __shared__ float bs[128];         // [i_local][l]
    int kg = blockIdx.x & 7;          // 8 chunks of 64 batches
    int mg = blockIdx.x >> 3;         // 144 groups of 64 ik
    int m0 = mg * 64;
    int kb0 = kg * 64;
    int t = threadIdx.x;
    if (t < 128) bs[t] = 0.f;
    for (int idx = t; idx < 1024; idx += 256) {
        int k = idx >> 4, mq = idx & 15;
        *(float4*)&xs2[k * 64 + mq * 4] =
            *(const float4*)(x + (size_t)(kb0 + k) * NIK + m0 + mq * 4);
    }
    for (int idx = t; idx < 64 * 28; idx += 256) {
        int k = idx / 28, cq = idx - k * 28;
        *(float4*)&vs[k * NLO + cq * 4] =
            *(const float4*)(v + (size_t)(kb0 + k) * NLO + cq * 4);
    }
    __syncthreads();
    int mq = t & 15;                  // 4 ik rows each
    int lq = t >> 4;                  // l = lq, cols o*16+lq
    float acc[4][7] = {};
    for (int k = 0; k < 64; ++k) {
        float4 x4 = *(const float4*)&xs2[k * 64 + mq * 4];
        const float* vr = &vs[k * NLO + lq];
        #pragma unroll
        for (int o = 0; o < 7; ++o) {
            float vv = vr[o * NL];
            acc[0][o] += x4.x * vv;
            acc[1][o] += x4.y * vv;
            acc[2][o] += x4.z * vv;
            acc[3][o] += x4.w * vv;
        }
    }
    float wsum = 0.f;
    #pragma unroll
    for (int j = 0; j < 4; ++j) {
        int ik = m0 + mq * 4 + j;
        const float* wr = w + (size_t)ik * NLO + lq * 7;
        #pragma unroll
        for (int o = 0; o < 7; ++o) wsum += wr[o] * acc[j][o];
    }
    int i_local = mq >> 1;            // (mq*4+j)/8, same for j=0..3
    atomicAdd(&bs[i_local * NL + lq], wsum);
    __syncthreads();
    if (t < 128)
        atomicAdd(&bij[(size_t)(m0 / 8 + (t >> 4)) * NL + (t & 15)], bs[t] * (1.0f / 512.0f));
}

extern "C" void kernel_launch(void* const* d_in, const int* in_sizes, int n_in,
                              void* d_out, int out_size, void* d_ws, size_t ws_size,
                              hipStream_t stream) {
    const float* x = (const float*)d_in[0];   // [512,1152,8] = [512][9216]
    const float* w = (const float*)d_in[1];   // [1152,8,16,7] = [9216][112]
    float* out = (float*)d_out;               // [512,7,16]
    float* ws = (float*)d_ws;
    float* f_b    = ws;                   // 18432
    float* f_c    = f_b + 18432;          // 18432
    float* f_v    = f_c + 18432;          // 57344
    float* f_part = f_v + 57344;          // 36*57344 = 2064384  (total ~8.6 MB)
    hipMemsetAsync(f_b, 0, 18432 * sizeof(float), stream);
    for (int it = 0; it < 3; ++it) {
        softmax_col<<<16, 256, 0, stream>>>(f_b, f_c);
        s_gemm<<<1152, 256, 0, stream>>>(x, w, f_c, f_part);
        squash_k<<<512, 128, 0, stream>>>(f_part, f_v, out, it == 2 ? 1 : 0);
        if (it < 2) g_fused<<<1152, 256, 0, stream>>>(x, f_v, w, f_b);
    }
}

// Round 5
// 199.845 us; speedup vs baseline: 6.0588x; 1.6103x over previous
//
#include <hip/hip_runtime.h>
#include <hip/hip_bf16.h>

// B=512, I=1152, K=8, L=16, O=7; IK=9216, LO=112.
// MFMA-based routing, bf16 inputs / fp32 accumulate:
//   wcT[lo][ik] = bf16(c[i,l]*w[ik,lo])          (per iter)
//   s[b,lo]     = x_bf . wcT  (MFMA, K-split partials, no LDS)
//   v           = squash(s);  vT[o16+l][b] bf16
//   G = xT_bf . vT (MFMA); bij[i,l] += (1/512) sum_{k,o} w[ik,l7+o]*G[ik,o16+l]
// Iter 3's bij update is dead code -> skipped.

#define NB 512
#define NI 1152
#define NLO 112
#define NIK 9216
#define KSPLIT 48            // 48 chunks of 192 k
#define SPART 57344          // 512*112

typedef __attribute__((ext_vector_type(8))) short bf16x8;
typedef __attribute__((ext_vector_type(4))) float f32x4;

__device__ __forceinline__ ushort f2bf(float f) {
    __hip_bfloat16 h = __float2bfloat16(f);
    return *(ushort*)&h;
}

// ---- c[i,l] = softmax over i of b[i,l] ----
__global__ void softmax_col(const float* __restrict__ b, float* __restrict__ c) {
    int l = blockIdx.x;          // 16 blocks
    int t = threadIdx.x;         // 256 threads
    __shared__ float red[256];
    float m = -1e30f;
    for (int i = t; i < NI; i += 256) m = fmaxf(m, b[i * 16 + l]);
    red[t] = m; __syncthreads();
    for (int s = 128; s > 0; s >>= 1) {
        if (t < s) red[t] = fmaxf(red[t], red[t + s]);
        __syncthreads();
    }
    m = red[0]; __syncthreads();
    float sum = 0.f;
    for (int i = t; i < NI; i += 256) sum += expf(b[i * 16 + l] - m);
    red[t] = sum; __syncthreads();
    for (int s = 128; s > 0; s >>= 1) {
        if (t < s) red[t] += red[t + s];
        __syncthreads();
    }
    float inv = 1.0f / red[0];
    for (int i = t; i < NI; i += 256) c[i * 16 + l] = expf(b[i * 16 + l] - m) * inv;
}

// ---- conv_x: x fp32 -> xbf [b][ik] and xT [ik][b], both bf16 ----
__global__ __launch_bounds__(256) void conv_x(const float* __restrict__ x,
                                              ushort* __restrict__ xbf,
                                              ushort* __restrict__ xT) {
    __shared__ ushort tile[64][68];
    int kg = blockIdx.x % 144, bg = blockIdx.x / 144;
    int k0 = kg * 64, b0 = bg * 64;
    int t = threadIdx.x;
    for (int e = t; e < 1024; e += 256) {
        int r = e >> 4, c4 = (e & 15) * 4;
        float4 f = *(const float4*)&x[(size_t)(b0 + r) * NIK + k0 + c4];
        ushort4 u = { f2bf(f.x), f2bf(f.y), f2bf(f.z), f2bf(f.w) };
        *(ushort4*)&xbf[(size_t)(b0 + r) * NIK + k0 + c4] = u;
        tile[r][c4] = u.x; tile[r][c4 + 1] = u.y; tile[r][c4 + 2] = u.z; tile[r][c4 + 3] = u.w;
    }
    __syncthreads();
    for (int e = t; e < 1024; e += 256) {
        int kr = e >> 4, c4 = (e & 15) * 4;
        ushort4 u = { tile[c4][kr], tile[c4 + 1][kr], tile[c4 + 2][kr], tile[c4 + 3][kr] };
        *(ushort4*)&xT[(size_t)(k0 + kr) * NB + b0 + c4] = u;
    }
}

// ---- conv_wc: wcT[lo][ik] = bf16(c[i,l] * w[ik][lo]) via LDS transpose ----
__global__ __launch_bounds__(256) void conv_wc(const float* __restrict__ c,
                                               const float* __restrict__ w,
                                               ushort* __restrict__ wcT) {
    __shared__ ushort tile[NLO][66];
    __shared__ float cs[128];
    int ik0 = blockIdx.x * 64;        // 144 blocks
    int t = threadIdx.x;
    if (t < 128) cs[t] = c[(size_t)(ik0 >> 3) * 16 + t];
    __syncthreads();
    for (int e = t; e < 7168; e += 256) {
        int ikl = e / NLO, lo = e - ikl * NLO;
        int il = ((ikl >> 3) << 4) + lo / 7;      // i_local*16 + l
        tile[lo][ikl] = f2bf(cs[il] * w[(size_t)(ik0 + ikl) * NLO + lo]);
    }
    __syncthreads();
    for (int e = t; e < 7168; e += 256) {
        int lo = e >> 6, ikl = e & 63;
        wcT[(size_t)lo * NIK + ik0 + ikl] = tile[lo][ikl];
    }
}

// ---- s_gemm: pure-MFMA, no LDS. wave = 16b M-tile x 7 N-tiles x 192k chunk ----
__global__ __launch_bounds__(256) void s_gemm(const ushort* __restrict__ xbf,
                                              const ushort* __restrict__ wcT,
                                              float* __restrict__ part) {
    int wid = blockIdx.x * 4 + (threadIdx.x >> 6);   // 384 blocks -> 1536 waves
    int lane = threadIdx.x & 63;
    int mt = wid & 31;               // 32 M-tiles of 16 batches
    int kc = wid >> 5;               // 48 K-chunks of 192
    int b0 = mt * 16, k0 = kc * 192;
    int row = lane & 15, quad = lane >> 4;
    const ushort* ap = xbf + (size_t)(b0 + row) * NIK + k0 + quad * 8;
    const ushort* bp = wcT + (size_t)row * NIK + k0 + quad * 8;   // + nt*16*NIK
    f32x4 acc[7];
    #pragma unroll
    for (int nt = 0; nt < 7; ++nt) acc[nt] = (f32x4){0.f, 0.f, 0.f, 0.f};
    for (int ks = 0; ks < 6; ++ks) {                 // 192/32 k-steps
        bf16x8 a = *(const bf16x8*)(ap + ks * 32);
        #pragma unroll
        for (int nt = 0; nt < 7; ++nt) {
            bf16x8 bfr = *(const bf16x8*)(bp + (size_t)nt * 16 * NIK + ks * 32);
            acc[nt] = __builtin_amdgcn_mfma_f32_16x16x32_bf16(a, bfr, acc[nt], 0, 0, 0);
        }
    }
    // D: m = b0 + quad*4 + r, n = nt*16 + row
    float* pp = part + (size_t)kc * SPART + (size_t)(b0 + quad * 4) * NLO + row;
    #pragma unroll
    for (int nt = 0; nt < 7; ++nt)
        #pragma unroll
        for (int r = 0; r < 4; ++r)
            pp[(size_t)r * NLO + nt * 16] = acc[nt][r];
}

// ---- fused K-split reduce + squash; writes vT bf16 (and out fp32 on last iter) ----
__global__ void squash_k(const float* __restrict__ part, ushort* __restrict__ vT,
                         float* __restrict__ out, int write_out) {
    int b = blockIdx.x;          // 512 blocks, 128 threads
    int t = threadIdx.x;
    __shared__ float sh[NLO];
    __shared__ float fac[16];
    float sv = 0.f;
    if (t < NLO) {
        const float* p = part + (size_t)b * NLO + t;
        #pragma unroll 8
        for (int kc = 0; kc < KSPLIT; ++kc) sv += p[(size_t)kc * SPART];
        sh[t] = sv;
    }
    __syncthreads();
    if (t < 16) {
        float sq = 0.f;
        #pragma unroll
        for (int o = 0; o < 7; ++o) { float e = sh[t * 7 + o]; sq += e * e; }
        fac[t] = sqrtf(sq) / (1.0f + sq);   // == (sq/(1+sq))/norm
    }
    __syncthreads();
    if (t < NLO) {
        int l = t / 7, o = t - l * 7;
        float vv = sv * fac[l];
        vT[(size_t)(o * 16 + l) * NB + b] = f2bf(vv);
        if (write_out) out[(size_t)b * NLO + o * 16 + l] = vv;
    }
}

// ---- g_fused: MFMA G-tile (16 ik x 112) over K=512, in-register w contraction ----
__global__ __launch_bounds__(256) void g_fused(const ushort* __restrict__ xT,
                                               const ushort* __restrict__ vT,
                                               const float* __restrict__ w,
                                               float* __restrict__ bij) {
    int wid = blockIdx.x * 4 + (threadIdx.x >> 6);   // 144 blocks -> 576 waves
    int lane = threadIdx.x & 63;
    int m0 = wid * 16;                               // ik tile base
    int row = lane & 15, quad = lane >> 4;
    const ushort* ap = xT + (size_t)(m0 + row) * NB + quad * 8;
    const ushort* bp = vT + (size_t)row * NB + quad * 8;    // + nt*16*NB
    f32x4 acc[7];
    #pragma unroll
    for (int nt = 0; nt < 7; ++nt) acc[nt] = (f32x4){0.f, 0.f, 0.f, 0.f};
    for (int ks = 0; ks < 16; ++ks) {                // 512/32
        bf16x8 a = *(const bf16x8*)(ap + ks * 32);
        #pragma unroll
        for (int nt = 0; nt < 7; ++nt) {
            bf16x8 bfr = *(const bf16x8*)(bp + (size_t)nt * 16 * NB + ks * 32);
            acc[nt] = __builtin_amdgcn_mfma_f32_16x16x32_bf16(a, bfr, acc[nt], 0, 0, 0);
        }
    }
    // lane holds G[ik = m0+quad*4+r][o*16+l] with o = nt, l = row
    float S = 0.f;
    #pragma unroll
    for (int r = 0; r < 4; ++r) {
        int ik = m0 + quad * 4 + r;
        const float* wr = w + (size_t)ik * NLO + row * 7;
        float p = 0.f;
        #pragma unroll
        for (int o = 0; o < 7; ++o) p += wr[o] * acc[o][r];
        S += p;
    }
    float Sp = __shfl_down(S, 16);                   // partner quad's 4-ik sum
    if ((quad & 1) == 0) {
        int i = (m0 >> 3) + (quad >> 1);             // wave owns i, i+1 exclusively
        bij[(size_t)i * 16 + row] += (S + Sp) * (1.0f / 512.0f);
    }
}

extern "C" void kernel_launch(void* const* d_in, const int* in_sizes, int n_in,
                              void* d_out, int out_size, void* d_ws, size_t ws_size,
                              hipStream_t stream) {
    const float* x = (const float*)d_in[0];   // [512][9216]
    const float* w = (const float*)d_in[1];   // [9216][112]
    float* out = (float*)d_out;               // [512][112]
    float* ws = (float*)d_ws;
    float*  f_b    = ws;                              // 18432
    float*  f_c    = f_b + 18432;                     // 18432
    float*  f_part = f_c + 18432;                     // 48*57344
    ushort* xbf    = (ushort*)(f_part + (size_t)KSPLIT * SPART);  // 512*9216
    ushort* xT     = xbf + (size_t)NB * NIK;          // 9216*512
    ushort* wcT    = xT + (size_t)NIK * NB;           // 112*9216
    ushort* vT     = wcT + (size_t)NLO * NIK;         // 112*512
    hipMemsetAsync(f_b, 0, 18432 * sizeof(float), stream);
    conv_x<<<1152, 256, 0, stream>>>(x, xbf, xT);
    for (int it = 0; it < 3; ++it) {
        softmax_col<<<16, 256, 0, stream>>>(f_b, f_c);
        conv_wc<<<144, 256, 0, stream>>>(f_c, w, wcT);
        s_gemm<<<384, 256, 0, stream>>>(xbf, wcT, f_part);
        squash_k<<<512, 128, 0, stream>>>(f_part, vT, out, it == 2 ? 1 : 0);
        if (it < 2) g_fused<<<144, 256, 0, stream>>>(xT, vT, w, f_b);
    }
}